// Round 7
// baseline (84.015 us; speedup 1.0000x reference)
//
#include <hip/hip_runtime.h>
#include <hip/hip_bf16.h>

#define CTX 2048
#define DM  1024
#define HD  64
#define BATCH 8
#define NSLOT 144   // sum over qi=0..31 of ceil((qi+1)/4)

typedef __attribute__((ext_vector_type(8))) short bf16x8;   // 8 bf16 = 4 VGPRs
typedef __attribute__((ext_vector_type(4))) float f32x4;

__device__ inline unsigned short f2bf(float f) {
    unsigned int u = __float_as_uint(f);
    unsigned int r = (u + 0x7fffu + ((u >> 16) & 1u)) >> 16;  // RNE
    return (unsigned short)r;
}

__device__ inline bf16x8 pack8(const float4& f0, const float4& f1) {
    union { bf16x8 v; __hip_bfloat162 h[4]; } u;
    u.h[0] = __float22bfloat162_rn(make_float2(f0.x, f0.y));
    u.h[1] = __float22bfloat162_rn(make_float2(f0.z, f0.w));
    u.h[2] = __float22bfloat162_rn(make_float2(f1.x, f1.y));
    u.h[3] = __float22bfloat162_rn(make_float2(f1.z, f1.w));
    return u.v;
}

__device__ inline uint2 pack4(const float4& f) {
    __hip_bfloat162 h0 = __float22bfloat162_rn(make_float2(f.x, f.y));
    __hip_bfloat162 h1 = __float22bfloat162_rn(make_float2(f.z, f.w));
    uint2 r;
    __builtin_memcpy(&r.x, &h0, 4);
    __builtin_memcpy(&r.y, &h1, 4);
    return r;
}

// prefix(qi) = number of chunk-blocks for q-blocks < qi (chunks of 4 kv-tiles)
__device__ __forceinline__ int chunk_prefix(int qi) {
    int q4 = qi >> 2, r = qi & 3;
    return qi + 2 * q4 * (q4 - 1) + q4 * r;
}

// ---------------- Kernel 0: coalesced transpose+convert W -> wt[192][1024] bf16 ------
__global__ __launch_bounds__(256) void wtrans(
    const float* __restrict__ Wq, const float* __restrict__ Wk,
    const float* __restrict__ Wv, unsigned short* __restrict__ wt)
{
    __shared__ __align__(16) unsigned short tile[64][72];
    const int m  = blockIdx.y;              // 0..2
    const int k0 = blockIdx.x * 64;
    const float* W = (m == 0) ? Wq : (m == 1) ? Wk : Wv;
    const int tid = threadIdx.x;
    const int c   = tid & 63, kk = tid >> 6;    // lanes span c: coalesced
    #pragma unroll
    for (int i = 0; i < 16; i++) {
        int kl = kk + i * 4;
        tile[c][kl] = f2bf(W[(size_t)(k0 + kl) * HD + c]);
    }
    __syncthreads();
    const int c2 = tid >> 2, seg = tid & 3;
    bf16x8 a = *reinterpret_cast<const bf16x8*>(&tile[c2][seg * 16]);
    bf16x8 b = *reinterpret_cast<const bf16x8*>(&tile[c2][seg * 16 + 8]);
    unsigned short* dst = wt + (size_t)(m * 64 + c2) * DM + k0 + seg * 16;
    *reinterpret_cast<bf16x8*>(dst)     = a;
    *reinterpret_cast<bf16x8*>(dst + 8) = b;
}

// ---------------- Kernel 1: QKV projection via bf16 MFMA, W direct from L2 ---------
// BM=32 x BN=192 x BK=64, 512 thr (8 warps 2x4, warp tile 16x48). Only x is LDS-
// staged (bf16, swizzled, double-buffered, 2-deep reg ping-pong). W B-frags are
// read straight from L2-resident wt each K-step (no LDS round-trip, no W barrier).
// q is written PRE-SCALED by 1024^-0.5 * log2(e) so attn can use exp2 directly.
__global__ __launch_bounds__(512) void qkv_gemm(
    const float* __restrict__ x, const unsigned short* __restrict__ wt,
    unsigned short* __restrict__ q, unsigned short* __restrict__ k,
    unsigned short* __restrict__ vt)
{
    __shared__ __align__(16) unsigned short xs[2][32 * 64];   // 8 KB total

    const int tid  = threadIdx.x, lane = tid & 63, w = tid >> 6;
    const int wr   = w >> 2, wc = w & 3;
    const int m0   = (int)blockIdx.x * 32;
    const int lcol = lane & 15, g = lane >> 4;

    // x staging: row = tid>>4 (0..31), 4 fp32 per thread
    const int xrow = tid >> 4, xseg = tid & 15;
    const float* xsrc = x + (size_t)(m0 + xrow) * DM + xseg * 4;
    const int xoff = (xrow * 128 + xseg * 8) ^ ((xrow & 7) << 4);

    // this thread's W-frag base: col = wc*48 + lcol (+cf*16), k offset g*8
    const unsigned short* wbase = wt + (size_t)(wc * 48 + lcol) * DM + g * 8;

    f32x4 acc[3];
    #pragma unroll
    for (int cf = 0; cf < 3; cf++) acc[cf] = (f32x4)0.f;

    float4 ra, rb;
    auto ld = [&](int k0) { return *reinterpret_cast<const float4*>(xsrc + k0); };
    auto st = [&](const float4& v, int buf) {
        *reinterpret_cast<uint2*>(reinterpret_cast<char*>(xs[buf]) + xoff) = pack4(v);
    };
    auto compute = [&](int buf, int k0) {
        char* xb = reinterpret_cast<char*>(xs[buf]);
        const int arow = wr * 16 + lcol;
        #pragma unroll
        for (int kc = 0; kc < 2; kc++) {
            bf16x8 a = *reinterpret_cast<const bf16x8*>(
                xb + ((arow * 128 + kc * 64 + g * 16) ^ ((arow & 7) << 4)));
            #pragma unroll
            for (int cf = 0; cf < 3; cf++) {
                bf16x8 b = *reinterpret_cast<const bf16x8*>(
                    wbase + (size_t)cf * 16 * DM + k0 + kc * 32);
                acc[cf] = __builtin_amdgcn_mfma_f32_16x16x32_bf16(a, b, acc[cf], 0, 0, 0);
            }
        }
    };

    // prologue: tile0 -> ra -> buf0; tile1 -> rb (in flight)
    ra = ld(0);
    rb = ld(64);
    st(ra, 0);
    __syncthreads();

    #pragma unroll 1
    for (int t = 0; t < 16; t += 2) {
        if (t + 2 < 16) ra = ld((t + 2) * 64);
        compute(0, t * 64);
        st(rb, 1);
        __syncthreads();
        if (t + 3 < 16) rb = ld((t + 3) * 64);
        compute(1, (t + 1) * 64);
        if (t + 2 < 16) st(ra, 0);
        __syncthreads();
    }

    const float QSCALE = 0.03125f * 1.4426950408889634f;  // 1024^-0.5 * log2(e)
    #pragma unroll
    for (int cf = 0; cf < 3; cf++)
        #pragma unroll
        for (int r = 0; r < 4; r++) {
            int row = m0 + wr * 16 + g * 4 + r;
            int col = wc * 48 + cf * 16 + lcol;
            int bb = row >> 11, tt = row & (CTX - 1);
            if (col < 64)       q[(size_t)row * HD + col] = f2bf(acc[cf][r] * QSCALE);
            else if (col < 128) k[(size_t)row * HD + (col - 64)] = f2bf(acc[cf][r]);
            else                vt[(size_t)bb * HD * CTX + (size_t)(col - 128) * CTX + tt] = f2bf(acc[cf][r]);
        }
}

// ---------------- Kernel 2: flash attention, uniform chunks, NO-MAX softmax --------
// Block = (qi, c): q-rows [qi*64,+64), kv tiles [4c, min(4c+3,qi)]. LDS exactly
// 32 KB -> 5 blocks/CU. pf is XOR-swizzled [16][64] f32 per warp (no pad).
__global__ __launch_bounds__(256) void attn_fa(
    const unsigned short* __restrict__ qg, const unsigned short* __restrict__ kg,
    const unsigned short* __restrict__ vtg, unsigned short* __restrict__ po,
    float* __restrict__ ml)
{
    __shared__ __align__(16) unsigned short ks[64 * 64];   // 8 KB
    __shared__ __align__(16) unsigned short vs[64 * 64];   // 8 KB
    __shared__ __align__(16) float pf[4][16 * 64];         // 16 KB, per-warp P

    const int tid  = threadIdx.x, lane = tid & 63, w = tid >> 6;
    const int bid  = blockIdx.x;            // 0..143 (slot)
    const int b    = blockIdx.y;
    int qi = 31;
    while (chunk_prefix(qi) > bid) qi--;
    const int c  = bid - chunk_prefix(qi);
    const int t0 = c * 4, t1 = min(t0 + 3, qi);
    const int rb = qi * 64 + w * 16;
    const int lcol = lane & 15, g = lane >> 4, lrow = g << 2;
    const size_t base  = (size_t)b * CTX * HD;
    const size_t vbase = (size_t)b * HD * CTX;
    char* ksb = reinterpret_cast<char*>(ks);
    char* vsb = reinterpret_cast<char*>(vs);
    char* pb  = reinterpret_cast<char*>(pf[w]);

    bf16x8 qa[2];
    #pragma unroll
    for (int kc = 0; kc < 2; kc++)
        qa[kc] = *reinterpret_cast<const bf16x8*>(
            qg + base + (size_t)(rb + lcol) * HD + kc * 32 + 8 * g);

    f32x4 o[4];
    #pragma unroll
    for (int dc = 0; dc < 4; dc++) o[dc] = (f32x4)0.f;
    float lsum[4] = {0.f, 0.f, 0.f, 0.f};

    const int r0 = tid >> 3, p0 = tid & 7, r1 = 32 + r0;
    bf16x8 kreg0, kreg1, vreg0, vreg1;

    auto ld = [&](int t) {
        const int j0 = t * 64;
        kreg0 = *reinterpret_cast<const bf16x8*>(kg + base + (size_t)(j0 + r0) * HD + p0 * 8);
        kreg1 = *reinterpret_cast<const bf16x8*>(kg + base + (size_t)(j0 + r1) * HD + p0 * 8);
        vreg0 = *reinterpret_cast<const bf16x8*>(vtg + vbase + (size_t)r0 * CTX + j0 + p0 * 8);
        vreg1 = *reinterpret_cast<const bf16x8*>(vtg + vbase + (size_t)r1 * CTX + j0 + p0 * 8);
    };
    auto st = [&]() {
        *reinterpret_cast<bf16x8*>(ksb + ((r0 * 128 + p0 * 16) ^ ((r0 & 7) << 4))) = kreg0;
        *reinterpret_cast<bf16x8*>(ksb + ((r1 * 128 + p0 * 16) ^ ((r1 & 7) << 4))) = kreg1;
        *reinterpret_cast<bf16x8*>(vsb + ((r0 * 128 + p0 * 16) ^ ((r0 & 7) << 4))) = vreg0;
        *reinterpret_cast<bf16x8*>(vsb + ((r1 * 128 + p0 * 16) ^ ((r1 & 7) << 4))) = vreg1;
    };

    ld(t0);
    for (int t = t0; t <= t1; t++) {
        __syncthreads();              // all warps done reading previous tile
        st();
        __syncthreads();              // tile t visible
        if (t < t1) ld(t + 1);        // prefetch overlaps compute below
        const int j0 = t * 64;

        // ---- S = Q K^T from LDS (Q pre-scaled by scale*log2e) ----
        f32x4 s[4];
        #pragma unroll
        for (int ch = 0; ch < 4; ch++) {
            s[ch] = (f32x4)0.f;
            #pragma unroll
            for (int kc = 0; kc < 2; kc++) {
                const int krow = ch * 16 + lcol;
                bf16x8 kf = *reinterpret_cast<const bf16x8*>(
                    ksb + ((krow * 128 + kc * 64 + g * 16) ^ ((krow & 7) << 4)));
                s[ch] = __builtin_amdgcn_mfma_f32_16x16x32_bf16(qa[kc], kf, s[ch], 0, 0, 0);
            }
        }

        // ---- causal mask (diagonal tile only) ----
        if (t == qi) {
            #pragma unroll
            for (int ch = 0; ch < 4; ch++)
                #pragma unroll
                for (int r = 0; r < 4; r++)
                    if (j0 + ch * 16 + lcol > rb + lrow + r) s[ch][r] = -1e30f;
        }

        // ---- p = exp2(s); accumulate l; P -> per-warp swizzled LDS ----
        #pragma unroll
        for (int ch = 0; ch < 4; ch++)
            #pragma unroll
            for (int r = 0; r < 4; r++) {
                float p = exp2f(s[ch][r]);    // masked -> 0
                lsum[r] += p;
                const int row = lrow + r;
                *reinterpret_cast<float*>(
                    pb + ((row * 256 + (ch * 16 + lcol) * 4) ^ ((row & 7) << 4))) = p;
            }

        // ---- read back A-frag + pack ----
        bf16x8 pa[2];
        const int rswz = (lcol & 7) << 4;
        #pragma unroll
        for (int kc = 0; kc < 2; kc++) {
            float4 f0 = *reinterpret_cast<const float4*>(
                pb + ((lcol * 256 + kc * 128 + g * 32) ^ rswz));
            float4 f1 = *reinterpret_cast<const float4*>(
                pb + ((lcol * 256 + kc * 128 + g * 32 + 16) ^ rswz));
            pa[kc] = pack8(f0, f1);
        }

        // ---- O += P V from LDS ----
        #pragma unroll
        for (int dc = 0; dc < 4; dc++)
            #pragma unroll
            for (int kc = 0; kc < 2; kc++) {
                const int vrow = dc * 16 + lcol;
                bf16x8 vf = *reinterpret_cast<const bf16x8*>(
                    vsb + ((vrow * 128 + kc * 64 + g * 16) ^ ((vrow & 7) << 4)));
                o[dc] = __builtin_amdgcn_mfma_f32_16x16x32_bf16(pa[kc], vf, o[dc], 0, 0, 0);
            }
    }

    // ---- store partials: o via pf (vectorized), l via shfl-reduce ----
    const size_t sl = (size_t)b * NSLOT + bid;
    #pragma unroll
    for (int dc = 0; dc < 4; dc++)
        #pragma unroll
        for (int r = 0; r < 4; r++) {
            const int row = lrow + r;
            *reinterpret_cast<float*>(
                pb + ((row * 256 + (dc * 16 + lcol) * 4) ^ ((row & 7) << 4))) = o[dc][r];
        }
    {
        const int orow = lcol;                 // 0..15; lane covers cols g*16..+15
        const int rswz = (orow & 7) << 4;
        float4 a0 = *reinterpret_cast<const float4*>(pb + ((orow * 256 + g * 64)      ^ rswz));
        float4 a1 = *reinterpret_cast<const float4*>(pb + ((orow * 256 + g * 64 + 16) ^ rswz));
        float4 a2 = *reinterpret_cast<const float4*>(pb + ((orow * 256 + g * 64 + 32) ^ rswz));
        float4 a3 = *reinterpret_cast<const float4*>(pb + ((orow * 256 + g * 64 + 48) ^ rswz));
        unsigned short* dst = po + sl * 4096 + (size_t)(w * 16 + orow) * 64 + g * 16;
        *reinterpret_cast<bf16x8*>(dst)     = pack8(a0, a1);
        *reinterpret_cast<bf16x8*>(dst + 8) = pack8(a2, a3);
    }
    #pragma unroll
    for (int r = 0; r < 4; r++) {
        float x = lsum[r];
        x += __shfl_xor(x, 1);
        x += __shfl_xor(x, 2);
        x += __shfl_xor(x, 4);
        x += __shfl_xor(x, 8);
        lsum[r] = x;
    }
    if (lcol == 0) {
        #pragma unroll
        for (int r = 0; r < 4; r++)
            ml[sl * 64 + w * 16 + lrow + r] = lsum[r];
    }
}

// ---------------- Kernel 3: merge chunk partials (plain sums, no exp) --------------
__global__ __launch_bounds__(256) void attn_merge(
    const unsigned short* __restrict__ po, const float* __restrict__ ml,
    float* __restrict__ out)
{
    const int qi = blockIdx.x, b = blockIdx.y;
    const int nch = (qi >> 2) + 1;
    const int s0  = chunk_prefix(qi);
    const int f8  = threadIdx.x & 7;     // col octet
    const int r0  = threadIdx.x >> 3;    // 0..31
    const size_t obase = (size_t)b * CTX * HD;

    #pragma unroll
    for (int half = 0; half < 2; half++) {
        const int row = half * 32 + r0;
        float L = 0.f;
        float acc[8];
        #pragma unroll
        for (int j = 0; j < 8; j++) acc[j] = 0.f;
        for (int cc = 0; cc < nch; cc++) {
            size_t sl = (size_t)b * NSLOT + s0 + cc;
            L += ml[sl * 64 + row];
            bf16x8 v8 = *reinterpret_cast<const bf16x8*>(po + sl * 4096 + (size_t)row * 64 + f8 * 8);
            #pragma unroll
            for (int j = 0; j < 8; j++)
                acc[j] += __uint_as_float(((unsigned)(unsigned short)v8[j]) << 16);
        }
        const float inv = 1.f / L;
        float4 o0 = make_float4(acc[0] * inv, acc[1] * inv, acc[2] * inv, acc[3] * inv);
        float4 o1 = make_float4(acc[4] * inv, acc[5] * inv, acc[6] * inv, acc[7] * inv);
        float* dst = out + obase + (size_t)(qi * 64 + row) * HD + f8 * 8;
        *reinterpret_cast<float4*>(dst)     = o0;
        *reinterpret_cast<float4*>(dst + 4) = o1;
    }
}

extern "C" void kernel_launch(void* const* d_in, const int* in_sizes, int n_in,
                              void* d_out, int out_size, void* d_ws, size_t ws_size,
                              hipStream_t stream) {
    // setup_inputs order: x, Wk, Wq, Wv
    const float* x  = (const float*)d_in[0];
    const float* Wk = (const float*)d_in[1];
    const float* Wq = (const float*)d_in[2];
    const float* Wv = (const float*)d_in[3];
    float* outp = (float*)d_out;

    const size_t n = (size_t)BATCH * CTX * HD;     // 1M elements each
    unsigned short* qb  = (unsigned short*)d_ws;
    unsigned short* kb  = qb + n;
    unsigned short* vtb = kb + n;
    unsigned short* wtb = vtb + n;                 // 192*1024
    unsigned short* pob = wtb + 192 * 1024;        // 8*144*4096 bf16
    float*          mlb = (float*)(pob + (size_t)BATCH * NSLOT * 4096);  // 8*144*64 f32

    wtrans<<<dim3(16, 3), dim3(256), 0, stream>>>(Wq, Wk, Wv, wtb);
    qkv_gemm<<<dim3(16384 / 32), dim3(512), 0, stream>>>(x, wtb, qb, kb, vtb);
    attn_fa<<<dim3(NSLOT, BATCH), dim3(256), 0, stream>>>(qb, kb, vtb, pob, mlb);
    attn_merge<<<dim3(32, BATCH), dim3(256), 0, stream>>>(pob, mlb, outp);
}

// Round 8
// 52.952 us; speedup vs baseline: 1.5866x; 1.5866x over previous
//
#include <hip/hip_runtime.h>
#include <hip/hip_bf16.h>

#define CTX 2048
#define DM  1024
#define HD  64
#define BATCH 8
#define NSLOT 144   // sum over qi=0..31 of ceil((qi+1)/4)

typedef __attribute__((ext_vector_type(8))) short bf16x8;   // 8 bf16 = 4 VGPRs
typedef __attribute__((ext_vector_type(4))) float f32x4;

__device__ inline unsigned short f2bf(float f) {
    unsigned int u = __float_as_uint(f);
    unsigned int r = (u + 0x7fffu + ((u >> 16) & 1u)) >> 16;  // RNE
    return (unsigned short)r;
}

__device__ inline bf16x8 pack8(const float4& f0, const float4& f1) {
    union { bf16x8 v; __hip_bfloat162 h[4]; } u;
    u.h[0] = __float22bfloat162_rn(make_float2(f0.x, f0.y));
    u.h[1] = __float22bfloat162_rn(make_float2(f0.z, f0.w));
    u.h[2] = __float22bfloat162_rn(make_float2(f1.x, f1.y));
    u.h[3] = __float22bfloat162_rn(make_float2(f1.z, f1.w));
    return u.v;
}

// prefix(qi) = number of chunk-blocks for q-blocks < qi (chunks of 4 kv-tiles)
__device__ __forceinline__ int chunk_prefix(int qi) {
    int q4 = qi >> 2, r = qi & 3;
    return qi + 2 * q4 * (q4 - 1) + q4 * r;
}

// ---------------- Kernel 0: coalesced transpose+convert W -> wt[192][1024] bf16 ------
__global__ __launch_bounds__(256) void wtrans(
    const float* __restrict__ Wq, const float* __restrict__ Wk,
    const float* __restrict__ Wv, unsigned short* __restrict__ wt)
{
    __shared__ __align__(16) unsigned short tile[64][72];
    const int m  = blockIdx.y;              // 0..2
    const int k0 = blockIdx.x * 64;
    const float* W = (m == 0) ? Wq : (m == 1) ? Wk : Wv;
    const int tid = threadIdx.x;
    const int c   = tid & 63, kk = tid >> 6;    // lanes span c: coalesced
    #pragma unroll
    for (int i = 0; i < 16; i++) {
        int kl = kk + i * 4;
        tile[c][kl] = f2bf(W[(size_t)(k0 + kl) * HD + c]);
    }
    __syncthreads();
    const int c2 = tid >> 2, seg = tid & 3;
    bf16x8 a = *reinterpret_cast<const bf16x8*>(&tile[c2][seg * 16]);
    bf16x8 b = *reinterpret_cast<const bf16x8*>(&tile[c2][seg * 16 + 8]);
    unsigned short* dst = wt + (size_t)(m * 64 + c2) * DM + k0 + seg * 16;
    *reinterpret_cast<bf16x8*>(dst)     = a;
    *reinterpret_cast<bf16x8*>(dst + 8) = b;
}

// ---------------- Kernel 1: QKV projection via bf16 MFMA, 2-deep pipeline ----------
// (REVERT to round-5 structure: W staged in LDS — the LDS round-trip is the
// latency-hiding mechanism; W-direct-from-L2 put ~200cyc loads on the MFMA
// critical path and cost 4x.)
// BM=32 x BN=192 x BK=64, 512 thr (8 warps 2x4, warp tile 16x48). Reg ping-pong
// (tile t+2 in flight) + LDS double-buffer, one barrier per K-step.
// q is written PRE-SCALED by 1024^-0.5 * log2(e) so attn can use exp2 directly.
__global__ __launch_bounds__(512) void qkv_gemm(
    const float* __restrict__ x, const unsigned short* __restrict__ wt,
    unsigned short* __restrict__ q, unsigned short* __restrict__ k,
    unsigned short* __restrict__ vt)
{
    __shared__ __align__(16) unsigned short wsT[2][192 * 64];  // 48 KB
    __shared__ __align__(16) unsigned short xsB[2][32 * 64];   // 8 KB

    const int tid  = threadIdx.x, lane = tid & 63, w = tid >> 6;
    const int wr   = w >> 2, wc = w & 3;
    const int m0   = (int)blockIdx.x * 32;
    const int lcol = lane & 15, g = lane >> 4;

    const int wc_c   = tid >> 3;        // W stage: col (+i*64)
    const int wc_par = tid & 7;         // W stage: k-part
    const int xrow   = tid >> 3;        // x stage: row (tid<256)
    const int xpar   = tid & 7;

    f32x4 acc[3];
    #pragma unroll
    for (int cf = 0; cf < 3; cf++) acc[cf] = (f32x4)0.f;

    bf16x8 rwA[3], rwB[3];
    float4 rxA0, rxA1, rxB0, rxB1;

    auto ldA = [&](int k0) {
        #pragma unroll
        for (int i = 0; i < 3; i++)
            rwA[i] = *reinterpret_cast<const bf16x8*>(wt + (size_t)(wc_c + i * 64) * DM + k0 + wc_par * 8);
        if (tid < 256) {
            const float* src = x + (size_t)(m0 + xrow) * DM + k0 + xpar * 8;
            rxA0 = *reinterpret_cast<const float4*>(src);
            rxA1 = *reinterpret_cast<const float4*>(src + 4);
        }
    };
    auto ldB = [&](int k0) {
        #pragma unroll
        for (int i = 0; i < 3; i++)
            rwB[i] = *reinterpret_cast<const bf16x8*>(wt + (size_t)(wc_c + i * 64) * DM + k0 + wc_par * 8);
        if (tid < 256) {
            const float* src = x + (size_t)(m0 + xrow) * DM + k0 + xpar * 8;
            rxB0 = *reinterpret_cast<const float4*>(src);
            rxB1 = *reinterpret_cast<const float4*>(src + 4);
        }
    };
    auto stA = [&](int buf) {
        char* wb = reinterpret_cast<char*>(wsT[buf]);
        char* xb = reinterpret_cast<char*>(xsB[buf]);
        #pragma unroll
        for (int i = 0; i < 3; i++) {
            int c = wc_c + i * 64;
            *reinterpret_cast<bf16x8*>(wb + ((c * 128 + wc_par * 16) ^ ((c & 7) << 4))) = rwA[i];
        }
        if (tid < 256)
            *reinterpret_cast<bf16x8*>(xb + ((xrow * 128 + xpar * 16) ^ ((xrow & 7) << 4))) = pack8(rxA0, rxA1);
    };
    auto stB = [&](int buf) {
        char* wb = reinterpret_cast<char*>(wsT[buf]);
        char* xb = reinterpret_cast<char*>(xsB[buf]);
        #pragma unroll
        for (int i = 0; i < 3; i++) {
            int c = wc_c + i * 64;
            *reinterpret_cast<bf16x8*>(wb + ((c * 128 + wc_par * 16) ^ ((c & 7) << 4))) = rwB[i];
        }
        if (tid < 256)
            *reinterpret_cast<bf16x8*>(xb + ((xrow * 128 + xpar * 16) ^ ((xrow & 7) << 4))) = pack8(rxB0, rxB1);
    };
    auto compute = [&](int buf) {
        char* wb = reinterpret_cast<char*>(wsT[buf]);
        char* xb = reinterpret_cast<char*>(xsB[buf]);
        #pragma unroll
        for (int kc = 0; kc < 2; kc++) {
            const int arow = wr * 16 + lcol;
            bf16x8 a = *reinterpret_cast<const bf16x8*>(
                xb + ((arow * 128 + kc * 64 + g * 16) ^ ((arow & 7) << 4)));
            #pragma unroll
            for (int cf = 0; cf < 3; cf++) {
                const int c = wc * 48 + cf * 16 + lcol;
                bf16x8 b = *reinterpret_cast<const bf16x8*>(
                    wb + ((c * 128 + kc * 64 + g * 16) ^ ((c & 7) << 4)));
                acc[cf] = __builtin_amdgcn_mfma_f32_16x16x32_bf16(a, b, acc[cf], 0, 0, 0);
            }
        }
    };

    // prologue: tile0 -> regA -> buf0; tile1 -> regB (in flight)
    ldA(0); ldB(64);
    stA(0);
    __syncthreads();

    #pragma unroll 1
    for (int t = 0; t < 16; t += 2) {
        if (t + 2 < 16) ldA((t + 2) * 64);   // regA free (stored)
        compute(0);                          // tile t from buf0
        stB(1);                              // tile t+1 -> buf1 (waits its loads)
        __syncthreads();
        if (t + 3 < 16) ldB((t + 3) * 64);   // regB free
        compute(1);                          // tile t+1 from buf1
        if (t + 2 < 16) stA(0);              // tile t+2 -> buf0
        __syncthreads();
    }

    const float QSCALE = 0.03125f * 1.4426950408889634f;  // 1024^-0.5 * log2(e)
    #pragma unroll
    for (int cf = 0; cf < 3; cf++)
        #pragma unroll
        for (int r = 0; r < 4; r++) {
            int row = m0 + wr * 16 + g * 4 + r;
            int col = wc * 48 + cf * 16 + lcol;
            int bb = row >> 11, tt = row & (CTX - 1);
            if (col < 64)       q[(size_t)row * HD + col] = f2bf(acc[cf][r] * QSCALE);
            else if (col < 128) k[(size_t)row * HD + (col - 64)] = f2bf(acc[cf][r]);
            else                vt[(size_t)bb * HD * CTX + (size_t)(col - 128) * CTX + tt] = f2bf(acc[cf][r]);
        }
}

// ---------------- Kernel 2: flash attention, uniform chunks, NO-MAX softmax --------
// Block = (qi, c): q-rows [qi*64,+64), kv tiles [4c, min(4c+3,qi)]. LDS exactly
// 32 KB -> 5 blocks/CU. pf is XOR-swizzled [16][64] f32 per warp (no pad).
__global__ __launch_bounds__(256) void attn_fa(
    const unsigned short* __restrict__ qg, const unsigned short* __restrict__ kg,
    const unsigned short* __restrict__ vtg, unsigned short* __restrict__ po,
    float* __restrict__ ml)
{
    __shared__ __align__(16) unsigned short ks[64 * 64];   // 8 KB
    __shared__ __align__(16) unsigned short vs[64 * 64];   // 8 KB
    __shared__ __align__(16) float pf[4][16 * 64];         // 16 KB, per-warp P

    const int tid  = threadIdx.x, lane = tid & 63, w = tid >> 6;
    const int bid  = blockIdx.x;            // 0..143 (slot)
    const int b    = blockIdx.y;
    int qi = 31;
    while (chunk_prefix(qi) > bid) qi--;
    const int c  = bid - chunk_prefix(qi);
    const int t0 = c * 4, t1 = min(t0 + 3, qi);
    const int rb = qi * 64 + w * 16;
    const int lcol = lane & 15, g = lane >> 4, lrow = g << 2;
    const size_t base  = (size_t)b * CTX * HD;
    const size_t vbase = (size_t)b * HD * CTX;
    char* ksb = reinterpret_cast<char*>(ks);
    char* vsb = reinterpret_cast<char*>(vs);
    char* pb  = reinterpret_cast<char*>(pf[w]);

    bf16x8 qa[2];
    #pragma unroll
    for (int kc = 0; kc < 2; kc++)
        qa[kc] = *reinterpret_cast<const bf16x8*>(
            qg + base + (size_t)(rb + lcol) * HD + kc * 32 + 8 * g);

    f32x4 o[4];
    #pragma unroll
    for (int dc = 0; dc < 4; dc++) o[dc] = (f32x4)0.f;
    float lsum[4] = {0.f, 0.f, 0.f, 0.f};

    const int r0 = tid >> 3, p0 = tid & 7, r1 = 32 + r0;
    bf16x8 kreg0, kreg1, vreg0, vreg1;

    auto ld = [&](int t) {
        const int j0 = t * 64;
        kreg0 = *reinterpret_cast<const bf16x8*>(kg + base + (size_t)(j0 + r0) * HD + p0 * 8);
        kreg1 = *reinterpret_cast<const bf16x8*>(kg + base + (size_t)(j0 + r1) * HD + p0 * 8);
        vreg0 = *reinterpret_cast<const bf16x8*>(vtg + vbase + (size_t)r0 * CTX + j0 + p0 * 8);
        vreg1 = *reinterpret_cast<const bf16x8*>(vtg + vbase + (size_t)r1 * CTX + j0 + p0 * 8);
    };
    auto st = [&]() {
        *reinterpret_cast<bf16x8*>(ksb + ((r0 * 128 + p0 * 16) ^ ((r0 & 7) << 4))) = kreg0;
        *reinterpret_cast<bf16x8*>(ksb + ((r1 * 128 + p0 * 16) ^ ((r1 & 7) << 4))) = kreg1;
        *reinterpret_cast<bf16x8*>(vsb + ((r0 * 128 + p0 * 16) ^ ((r0 & 7) << 4))) = vreg0;
        *reinterpret_cast<bf16x8*>(vsb + ((r1 * 128 + p0 * 16) ^ ((r1 & 7) << 4))) = vreg1;
    };

    ld(t0);
    for (int t = t0; t <= t1; t++) {
        __syncthreads();              // all warps done reading previous tile
        st();
        __syncthreads();              // tile t visible
        if (t < t1) ld(t + 1);        // prefetch overlaps compute below
        const int j0 = t * 64;

        // ---- S = Q K^T from LDS (Q pre-scaled by scale*log2e) ----
        f32x4 s[4];
        #pragma unroll
        for (int ch = 0; ch < 4; ch++) {
            s[ch] = (f32x4)0.f;
            #pragma unroll
            for (int kc = 0; kc < 2; kc++) {
                const int krow = ch * 16 + lcol;
                bf16x8 kf = *reinterpret_cast<const bf16x8*>(
                    ksb + ((krow * 128 + kc * 64 + g * 16) ^ ((krow & 7) << 4)));
                s[ch] = __builtin_amdgcn_mfma_f32_16x16x32_bf16(qa[kc], kf, s[ch], 0, 0, 0);
            }
        }

        // ---- causal mask (diagonal tile only) ----
        if (t == qi) {
            #pragma unroll
            for (int ch = 0; ch < 4; ch++)
                #pragma unroll
                for (int r = 0; r < 4; r++)
                    if (j0 + ch * 16 + lcol > rb + lrow + r) s[ch][r] = -1e30f;
        }

        // ---- p = exp2(s); accumulate l; P -> per-warp swizzled LDS ----
        #pragma unroll
        for (int ch = 0; ch < 4; ch++)
            #pragma unroll
            for (int r = 0; r < 4; r++) {
                float p = exp2f(s[ch][r]);    // masked -> 0
                lsum[r] += p;
                const int row = lrow + r;
                *reinterpret_cast<float*>(
                    pb + ((row * 256 + (ch * 16 + lcol) * 4) ^ ((row & 7) << 4))) = p;
            }

        // ---- read back A-frag + pack ----
        bf16x8 pa[2];
        const int rswz = (lcol & 7) << 4;
        #pragma unroll
        for (int kc = 0; kc < 2; kc++) {
            float4 f0 = *reinterpret_cast<const float4*>(
                pb + ((lcol * 256 + kc * 128 + g * 32) ^ rswz));
            float4 f1 = *reinterpret_cast<const float4*>(
                pb + ((lcol * 256 + kc * 128 + g * 32 + 16) ^ rswz));
            pa[kc] = pack8(f0, f1);
        }

        // ---- O += P V from LDS ----
        #pragma unroll
        for (int dc = 0; dc < 4; dc++)
            #pragma unroll
            for (int kc = 0; kc < 2; kc++) {
                const int vrow = dc * 16 + lcol;
                bf16x8 vf = *reinterpret_cast<const bf16x8*>(
                    vsb + ((vrow * 128 + kc * 64 + g * 16) ^ ((vrow & 7) << 4)));
                o[dc] = __builtin_amdgcn_mfma_f32_16x16x32_bf16(pa[kc], vf, o[dc], 0, 0, 0);
            }
    }

    // ---- store partials: o via pf (vectorized), l via shfl-reduce ----
    const size_t sl = (size_t)b * NSLOT + bid;
    #pragma unroll
    for (int dc = 0; dc < 4; dc++)
        #pragma unroll
        for (int r = 0; r < 4; r++) {
            const int row = lrow + r;
            *reinterpret_cast<float*>(
                pb + ((row * 256 + (dc * 16 + lcol) * 4) ^ ((row & 7) << 4))) = o[dc][r];
        }
    {
        const int orow = lcol;                 // 0..15; lane covers cols g*16..+15
        const int rswz = (orow & 7) << 4;
        float4 a0 = *reinterpret_cast<const float4*>(pb + ((orow * 256 + g * 64)      ^ rswz));
        float4 a1 = *reinterpret_cast<const float4*>(pb + ((orow * 256 + g * 64 + 16) ^ rswz));
        float4 a2 = *reinterpret_cast<const float4*>(pb + ((orow * 256 + g * 64 + 32) ^ rswz));
        float4 a3 = *reinterpret_cast<const float4*>(pb + ((orow * 256 + g * 64 + 48) ^ rswz));
        unsigned short* dst = po + sl * 4096 + (size_t)(w * 16 + orow) * 64 + g * 16;
        *reinterpret_cast<bf16x8*>(dst)     = pack8(a0, a1);
        *reinterpret_cast<bf16x8*>(dst + 8) = pack8(a2, a3);
    }
    #pragma unroll
    for (int r = 0; r < 4; r++) {
        float x = lsum[r];
        x += __shfl_xor(x, 1);
        x += __shfl_xor(x, 2);
        x += __shfl_xor(x, 4);
        x += __shfl_xor(x, 8);
        lsum[r] = x;
    }
    if (lcol == 0) {
        #pragma unroll
        for (int r = 0; r < 4; r++)
            ml[sl * 64 + w * 16 + lrow + r] = lsum[r];
    }
}

// ---------------- Kernel 3: merge chunk partials (plain sums, no exp) --------------
__global__ __launch_bounds__(256) void attn_merge(
    const unsigned short* __restrict__ po, const float* __restrict__ ml,
    float* __restrict__ out)
{
    const int qi = blockIdx.x, b = blockIdx.y;
    const int nch = (qi >> 2) + 1;
    const int s0  = chunk_prefix(qi);
    const int f8  = threadIdx.x & 7;     // col octet
    const int r0  = threadIdx.x >> 3;    // 0..31
    const size_t obase = (size_t)b * CTX * HD;

    #pragma unroll
    for (int half = 0; half < 2; half++) {
        const int row = half * 32 + r0;
        float L = 0.f;
        float acc[8];
        #pragma unroll
        for (int j = 0; j < 8; j++) acc[j] = 0.f;
        for (int cc = 0; cc < nch; cc++) {
            size_t sl = (size_t)b * NSLOT + s0 + cc;
            L += ml[sl * 64 + row];
            bf16x8 v8 = *reinterpret_cast<const bf16x8*>(po + sl * 4096 + (size_t)row * 64 + f8 * 8);
            #pragma unroll
            for (int j = 0; j < 8; j++)
                acc[j] += __uint_as_float(((unsigned)(unsigned short)v8[j]) << 16);
        }
        const float inv = 1.f / L;
        float4 o0 = make_float4(acc[0] * inv, acc[1] * inv, acc[2] * inv, acc[3] * inv);
        float4 o1 = make_float4(acc[4] * inv, acc[5] * inv, acc[6] * inv, acc[7] * inv);
        float* dst = out + obase + (size_t)(qi * 64 + row) * HD + f8 * 8;
        *reinterpret_cast<float4*>(dst)     = o0;
        *reinterpret_cast<float4*>(dst + 4) = o1;
    }
}

extern "C" void kernel_launch(void* const* d_in, const int* in_sizes, int n_in,
                              void* d_out, int out_size, void* d_ws, size_t ws_size,
                              hipStream_t stream) {
    // setup_inputs order: x, Wk, Wq, Wv
    const float* x  = (const float*)d_in[0];
    const float* Wk = (const float*)d_in[1];
    const float* Wq = (const float*)d_in[2];
    const float* Wv = (const float*)d_in[3];
    float* outp = (float*)d_out;

    const size_t n = (size_t)BATCH * CTX * HD;     // 1M elements each
    unsigned short* qb  = (unsigned short*)d_ws;
    unsigned short* kb  = qb + n;
    unsigned short* vtb = kb + n;
    unsigned short* wtb = vtb + n;                 // 192*1024
    unsigned short* pob = wtb + 192 * 1024;        // 8*144*4096 bf16
    float*          mlb = (float*)(pob + (size_t)BATCH * NSLOT * 4096);  // 8*144*64 f32

    wtrans<<<dim3(16, 3), dim3(256), 0, stream>>>(Wq, Wk, Wv, wtb);
    qkv_gemm<<<dim3(16384 / 32), dim3(512), 0, stream>>>(x, wtb, qb, kb, vtb);
    attn_fa<<<dim3(NSLOT, BATCH), dim3(256), 0, stream>>>(qb, kb, vtb, pob, mlb);
    attn_merge<<<dim3(32, BATCH), dim3(256), 0, stream>>>(pob, mlb, outp);
}